// Round 8
// baseline (48.989 us; speedup 1.0000x reference)
//
#include <hip/hip_runtime.h>

#define HWPIX 4096   // 64*64 pixels
#define SEQ   77
#define NBLK_SELF 4096

// bilinear coord for 64 -> 256 upsample (align_corners=False), i in [0,255]
__device__ __forceinline__ void coord(int i, int& i0, int& i1, float& w) {
    float s = fminf(fmaxf(0.25f * (float)i - 0.375f, 0.0f), 63.0f);
    i0 = (int)s;              // s >= 0 so trunc == floor
    i1 = min(i0 + 1, 63);
    w = s - (float)i0;
}

// Kernel 1: upsample-max, 64 blocks = 8 channels x 8 row-groups.
__global__ __launch_bounds__(256) void kmax(const float* __restrict__ attn,
                                            float* __restrict__ ws_max) {
    __shared__ float tile[10 * 64];
    __shared__ float red[4];
    const int c = blockIdx.x >> 3;
    const int g = blockIdx.x & 7;
    const int tok = c + 1;
    const int t = threadIdx.x;
    const int ybase = 8 * g - 1;

    for (int idx = t; idx < 640; idx += 256) {
        int rr = idx >> 6, x = idx & 63;
        int y = min(max(ybase + rr, 0), 63);
        tile[idx] = attn[(y * 64 + x) * SEQ + tok];
    }
    __syncthreads();

    int x0, x1; float wx;
    coord(t, x0, x1, wx);
    float m = -1e30f;
    int cy0 = -99, cy1 = -99;
    float r0 = 0.f, r1 = 0.f;
    for (int i = 32 * g; i < 32 * g + 32; ++i) {
        int y0, y1; float wy;
        coord(i, y0, y1, wy);
        if (y0 != cy0 || y1 != cy1) {
            int l0 = y0 - ybase, l1 = y1 - ybase;
            if (y0 == cy1) r0 = r1;
            else r0 = tile[l0 * 64 + x0] * (1.f - wx) + tile[l0 * 64 + x1] * wx;
            if (y1 == y0) r1 = r0;
            else r1 = tile[l1 * 64 + x0] * (1.f - wx) + tile[l1 * 64 + x1] * wx;
            cy0 = y0; cy1 = y1;
        }
        m = fmaxf(m, r0 * (1.f - wy) + r1 * wy);
    }
    #pragma unroll
    for (int off = 1; off < 64; off <<= 1)
        m = fmaxf(m, __shfl_xor(m, off, 64));
    if ((t & 63) == 0) red[t >> 6] = m;
    __syncthreads();
    if (t == 0) {
        float bm = fmaxf(fmaxf(red[0], red[1]), fmaxf(red[2], red[3]));
        atomicMax((int*)&ws_max[c], __float_as_int(bm));  // nonneg floats
    }
}

// Kernel 2: gates (blocks 0..127) and cross-attn MSE (blocks 128..135).
__global__ __launch_bounds__(256) void kgates(const float* __restrict__ attn,
                                              const float* __restrict__ attn_e,
                                              const float* __restrict__ ws_max,
                                              float* __restrict__ wj,
                                              float* __restrict__ ws_cross) {
    const int bid = blockIdx.x;
    const int t = threadIdx.x;
    if (bid < 128) {
        const int c = bid >> 4;
        const int tok = c + 1;
        const bool is_tok = (tok == 2) || (tok == 5);
        const float lim = ws_max[c] * (is_tok ? 0.85f : 0.95f);
        const int j = (bid & 15) * 256 + t;
        const int y = j >> 6, x = j & 63;
        bool gate = false;
        #pragma unroll
        for (int di = 1; di <= 2; ++di) {
            int y0, y1; float wy;
            coord(4 * y + di, y0, y1, wy);
            #pragma unroll
            for (int dj = 1; dj <= 2; ++dj) {
                int xa, xb; float wxv;
                coord(4 * x + dj, xa, xb, wxv);
                float v00 = attn[(y0 * 64 + xa) * SEQ + tok];
                float v01 = attn[(y0 * 64 + xb) * SEQ + tok];
                float v10 = attn[(y1 * 64 + xa) * SEQ + tok];
                float v11 = attn[(y1 * 64 + xb) * SEQ + tok];
                float top = v00 * (1.f - wxv) + v01 * wxv;
                float bot = v10 * (1.f - wxv) + v11 * wxv;
                float u = top * (1.f - wy) + bot * wy;
                gate = gate || (u >= lim);
            }
        }
        if (gate) atomicAdd(&wj[j], is_tok ? -1.f : 1.f);
    } else {
        __shared__ float red[4];
        const int tok = bid - 128 + 1;
        const bool is_tok = (tok == 2) || (tok == 5);
        float sum = 0.f;
        #pragma unroll
        for (int kk = 0; kk < 16; ++kk) {
            int p = t + kk * 256;
            float d = attn[p * SEQ + tok] - attn_e[p * SEQ + tok];
            sum += d * d;
        }
        #pragma unroll
        for (int off = 1; off < 64; off <<= 1) sum += __shfl_xor(sum, off, 64);
        if ((t & 63) == 0) red[t >> 6] = sum;
        __syncthreads();
        if (t == 0) {
            float tot = red[0] + red[1] + red[2] + red[3];
            atomicAdd(ws_cross, (is_tok ? -1.f : 1.f) * tot);
        }
    }
}

// Kernel 3: streaming pass, 4096 blocks — block b reads exactly ONE 16KB row
// of each array (f = b*1024 + k*256 + t, k=0..3). Two generations of blocks
// per CU sustain the request stream as the first generation drains (vs the
// single-burst one-round dispatch that plateaued at 1.6 TB/s HBM).
// Column-quad of load k is exactly k*256+t -> vw[k] direct.
__global__ __launch_bounds__(256) void kself(const float4* __restrict__ a,
                                             const float4* __restrict__ b,
                                             const float* __restrict__ wj,
                                             float* __restrict__ ws_partial) {
    __shared__ float red[4];
    const int t = threadIdx.x;
    const int base = blockIdx.x * 1024 + t;
    float4 va[4], vb[4];
    #pragma unroll
    for (int k = 0; k < 4; ++k) va[k] = a[base + k * 256];
    #pragma unroll
    for (int k = 0; k < 4; ++k) vb[k] = b[base + k * 256];
    const float4* wj4 = (const float4*)wj;
    float4 vw[4];
    #pragma unroll
    for (int k = 0; k < 4; ++k) vw[k] = wj4[k * 256 + t];
    float sum = 0.f;
    #pragma unroll
    for (int k = 0; k < 4; ++k) {
        float d0 = va[k].x - vb[k].x;
        float d1 = va[k].y - vb[k].y;
        float d2 = va[k].z - vb[k].z;
        float d3 = va[k].w - vb[k].w;
        sum += vw[k].x * d0 * d0 + vw[k].y * d1 * d1
             + vw[k].z * d2 * d2 + vw[k].w * d3 * d3;
    }
    #pragma unroll
    for (int off = 1; off < 64; off <<= 1) sum += __shfl_xor(sum, off, 64);
    if ((t & 63) == 0) red[t >> 6] = sum;
    __syncthreads();
    if (t == 0)
        ws_partial[blockIdx.x] = red[0] + red[1] + red[2] + red[3];
}

// Kernel 4: finalize — 1 block sums 4096 partials + cross term, writes out.
__global__ __launch_bounds__(256) void kfin(const float* __restrict__ ws_partial,
                                            const float* __restrict__ ws_cross,
                                            float* __restrict__ out) {
    __shared__ float red[4];
    const int t = threadIdx.x;
    float sum = 0.f;
    #pragma unroll
    for (int k = 0; k < 16; ++k) sum += ws_partial[t + k * 256];
    #pragma unroll
    for (int off = 1; off < 64; off <<= 1) sum += __shfl_xor(sum, off, 64);
    if ((t & 63) == 0) red[t >> 6] = sum;
    __syncthreads();
    if (t == 0) {
        float tot = red[0] + red[1] + red[2] + red[3] + ws_cross[0];
        out[0] = tot * (1.0f / HWPIX);
    }
}

extern "C" void kernel_launch(void* const* d_in, const int* in_sizes, int n_in,
                              void* d_out, int out_size, void* d_ws, size_t ws_size,
                              hipStream_t stream) {
    const float* attn   = (const float*)d_in[0];
    const float* attn_e = (const float*)d_in[1];
    const float* sa     = (const float*)d_in[2];
    const float* sae    = (const float*)d_in[3];
    float* out = (float*)d_out;
    float* wj       = (float*)d_ws;               // [0,    4096) gate weights
    float* ws_max   = wj + HWPIX;                 // [4096, 4104) channel maxima
    float* ws_cross = wj + HWPIX + 8;             // [4104, 4105) cross accumulator
    float* ws_part  = wj + 4352;                  // [4352, 8448) kself partials

    hipMemsetAsync(wj, 0, (HWPIX + 16) * sizeof(float), stream);
    kmax  <<<64,        256, 0, stream>>>(attn, ws_max);
    kgates<<<136,       256, 0, stream>>>(attn, attn_e, ws_max, wj, ws_cross);
    kself <<<NBLK_SELF, 256, 0, stream>>>((const float4*)sa, (const float4*)sae, wj, ws_part);
    kfin  <<<1,         256, 0, stream>>>(ws_part, ws_cross, out);
}

// Round 9
// 41.247 us; speedup vs baseline: 1.1877x; 1.1877x over previous
//
#include <hip/hip_runtime.h>

#define HWPIX 4096   // 64*64 pixels
#define SEQ   77
#define NBLK_SELF 4096

typedef float f32x4 __attribute__((ext_vector_type(4)));

// bilinear coord for 64 -> 256 upsample (align_corners=False), i in [0,255]
__device__ __forceinline__ void coord(int i, int& i0, int& i1, float& w) {
    float s = fminf(fmaxf(0.25f * (float)i - 0.375f, 0.0f), 63.0f);
    i0 = (int)s;              // s >= 0 so trunc == floor
    i1 = min(i0 + 1, 63);
    w = s - (float)i0;
}

// Kernel 1: upsample-max, 64 blocks = 8 channels x 8 row-groups.
__global__ __launch_bounds__(256) void kmax(const float* __restrict__ attn,
                                            float* __restrict__ ws_max) {
    __shared__ float tile[10 * 64];
    __shared__ float red[4];
    const int c = blockIdx.x >> 3;
    const int g = blockIdx.x & 7;
    const int tok = c + 1;
    const int t = threadIdx.x;
    const int ybase = 8 * g - 1;

    for (int idx = t; idx < 640; idx += 256) {
        int rr = idx >> 6, x = idx & 63;
        int y = min(max(ybase + rr, 0), 63);
        tile[idx] = attn[(y * 64 + x) * SEQ + tok];
    }
    __syncthreads();

    int x0, x1; float wx;
    coord(t, x0, x1, wx);
    float m = -1e30f;
    int cy0 = -99, cy1 = -99;
    float r0 = 0.f, r1 = 0.f;
    for (int i = 32 * g; i < 32 * g + 32; ++i) {
        int y0, y1; float wy;
        coord(i, y0, y1, wy);
        if (y0 != cy0 || y1 != cy1) {
            int l0 = y0 - ybase, l1 = y1 - ybase;
            if (y0 == cy1) r0 = r1;
            else r0 = tile[l0 * 64 + x0] * (1.f - wx) + tile[l0 * 64 + x1] * wx;
            if (y1 == y0) r1 = r0;
            else r1 = tile[l1 * 64 + x0] * (1.f - wx) + tile[l1 * 64 + x1] * wx;
            cy0 = y0; cy1 = y1;
        }
        m = fmaxf(m, r0 * (1.f - wy) + r1 * wy);
    }
    #pragma unroll
    for (int off = 1; off < 64; off <<= 1)
        m = fmaxf(m, __shfl_xor(m, off, 64));
    if ((t & 63) == 0) red[t >> 6] = m;
    __syncthreads();
    if (t == 0) {
        float bm = fmaxf(fmaxf(red[0], red[1]), fmaxf(red[2], red[3]));
        atomicMax((int*)&ws_max[c], __float_as_int(bm));  // nonneg floats
    }
}

// Kernel 2: gates (blocks 0..127) and cross-attn MSE (blocks 128..135).
__global__ __launch_bounds__(256) void kgates(const float* __restrict__ attn,
                                              const float* __restrict__ attn_e,
                                              const float* __restrict__ ws_max,
                                              float* __restrict__ wj,
                                              float* __restrict__ ws_cross) {
    const int bid = blockIdx.x;
    const int t = threadIdx.x;
    if (bid < 128) {
        const int c = bid >> 4;
        const int tok = c + 1;
        const bool is_tok = (tok == 2) || (tok == 5);
        const float lim = ws_max[c] * (is_tok ? 0.85f : 0.95f);
        const int j = (bid & 15) * 256 + t;
        const int y = j >> 6, x = j & 63;
        bool gate = false;
        #pragma unroll
        for (int di = 1; di <= 2; ++di) {
            int y0, y1; float wy;
            coord(4 * y + di, y0, y1, wy);
            #pragma unroll
            for (int dj = 1; dj <= 2; ++dj) {
                int xa, xb; float wxv;
                coord(4 * x + dj, xa, xb, wxv);
                float v00 = attn[(y0 * 64 + xa) * SEQ + tok];
                float v01 = attn[(y0 * 64 + xb) * SEQ + tok];
                float v10 = attn[(y1 * 64 + xa) * SEQ + tok];
                float v11 = attn[(y1 * 64 + xb) * SEQ + tok];
                float top = v00 * (1.f - wxv) + v01 * wxv;
                float bot = v10 * (1.f - wxv) + v11 * wxv;
                float u = top * (1.f - wy) + bot * wy;
                gate = gate || (u >= lim);
            }
        }
        if (gate) atomicAdd(&wj[j], is_tok ? -1.f : 1.f);
    } else {
        __shared__ float red[4];
        const int tok = bid - 128 + 1;
        const bool is_tok = (tok == 2) || (tok == 5);
        float sum = 0.f;
        #pragma unroll
        for (int kk = 0; kk < 16; ++kk) {
            int p = t + kk * 256;
            float d = attn[p * SEQ + tok] - attn_e[p * SEQ + tok];
            sum += d * d;
        }
        #pragma unroll
        for (int off = 1; off < 64; off <<= 1) sum += __shfl_xor(sum, off, 64);
        if ((t & 63) == 0) red[t >> 6] = sum;
        __syncthreads();
        if (t == 0) {
            float tot = red[0] + red[1] + red[2] + red[3];
            atomicAdd(ws_cross, (is_tok ? -1.f : 1.f) * tot);
        }
    }
}

// Kernel 3: streaming pass, 4096 blocks, NON-TEMPORAL a/b loads (bypass
// cache allocation on the read path — testing the ~3.1 TB/s read-stream cap).
// Block b reads exactly ONE 16KB row of each array; col-quad of load k is
// k*256+t -> vw[k] direct.
__global__ __launch_bounds__(256) void kself(const float4* __restrict__ a,
                                             const float4* __restrict__ b,
                                             const float* __restrict__ wj,
                                             float* __restrict__ ws_partial) {
    __shared__ float red[4];
    const int t = threadIdx.x;
    const int base = blockIdx.x * 1024 + t;
    const f32x4* av = (const f32x4*)a;
    const f32x4* bv = (const f32x4*)b;
    f32x4 va[4], vb[4];
    #pragma unroll
    for (int k = 0; k < 4; ++k) va[k] = __builtin_nontemporal_load(&av[base + k * 256]);
    #pragma unroll
    for (int k = 0; k < 4; ++k) vb[k] = __builtin_nontemporal_load(&bv[base + k * 256]);
    const float4* wj4 = (const float4*)wj;
    float4 vw[4];
    #pragma unroll
    for (int k = 0; k < 4; ++k) vw[k] = wj4[k * 256 + t];
    float sum = 0.f;
    #pragma unroll
    for (int k = 0; k < 4; ++k) {
        float d0 = va[k].x - vb[k].x;
        float d1 = va[k].y - vb[k].y;
        float d2 = va[k].z - vb[k].z;
        float d3 = va[k].w - vb[k].w;
        sum += vw[k].x * d0 * d0 + vw[k].y * d1 * d1
             + vw[k].z * d2 * d2 + vw[k].w * d3 * d3;
    }
    #pragma unroll
    for (int off = 1; off < 64; off <<= 1) sum += __shfl_xor(sum, off, 64);
    if ((t & 63) == 0) red[t >> 6] = sum;
    __syncthreads();
    if (t == 0)
        ws_partial[blockIdx.x] = red[0] + red[1] + red[2] + red[3];
}

// Kernel 4: finalize — 1 block sums 4096 partials + cross term, writes out.
__global__ __launch_bounds__(256) void kfin(const float* __restrict__ ws_partial,
                                            const float* __restrict__ ws_cross,
                                            float* __restrict__ out) {
    __shared__ float red[4];
    const int t = threadIdx.x;
    float sum = 0.f;
    #pragma unroll
    for (int k = 0; k < 16; ++k) sum += ws_partial[t + k * 256];
    #pragma unroll
    for (int off = 1; off < 64; off <<= 1) sum += __shfl_xor(sum, off, 64);
    if ((t & 63) == 0) red[t >> 6] = sum;
    __syncthreads();
    if (t == 0) {
        float tot = red[0] + red[1] + red[2] + red[3] + ws_cross[0];
        out[0] = tot * (1.0f / HWPIX);
    }
}

extern "C" void kernel_launch(void* const* d_in, const int* in_sizes, int n_in,
                              void* d_out, int out_size, void* d_ws, size_t ws_size,
                              hipStream_t stream) {
    const float* attn   = (const float*)d_in[0];
    const float* attn_e = (const float*)d_in[1];
    const float* sa     = (const float*)d_in[2];
    const float* sae    = (const float*)d_in[3];
    float* out = (float*)d_out;
    float* wj       = (float*)d_ws;               // [0,    4096) gate weights
    float* ws_max   = wj + HWPIX;                 // [4096, 4104) channel maxima
    float* ws_cross = wj + HWPIX + 8;             // [4104, 4105) cross accumulator
    float* ws_part  = wj + 4352;                  // [4352, 8448) kself partials

    hipMemsetAsync(wj, 0, (HWPIX + 16) * sizeof(float), stream);
    kmax  <<<64,        256, 0, stream>>>(attn, ws_max);
    kgates<<<136,       256, 0, stream>>>(attn, attn_e, ws_max, wj, ws_cross);
    kself <<<NBLK_SELF, 256, 0, stream>>>((const float4*)sa, (const float4*)sae, wj, ws_part);
    kfin  <<<1,         256, 0, stream>>>(ws_part, ws_cross, out);
}

// Round 12
// 38.236 us; speedup vs baseline: 1.2812x; 1.0787x over previous
//
#include <hip/hip_runtime.h>

#define HWPIX 4096   // 64*64 pixels
#define SEQ   77
#define NBLK_SELF 4096

typedef float f32x4 __attribute__((ext_vector_type(4)));

// bilinear coord for 64 -> 256 upsample (align_corners=False), i in [0,255]
__device__ __forceinline__ void coord(int i, int& i0, int& i1, float& w) {
    float s = fminf(fmaxf(0.25f * (float)i - 0.375f, 0.0f), 63.0f);
    i0 = (int)s;              // s >= 0 so trunc == floor
    i1 = min(i0 + 1, 63);
    w = s - (float)i0;
}

// Kernel 1: upsample-max partials, 64 blocks = 8 channels x 8 row-groups.
// Plain store of the block max -> no atomics, no init needed.
__global__ __launch_bounds__(256) void kmax(const float* __restrict__ attn,
                                            float* __restrict__ ws_maxpart) {
    __shared__ float tile[10 * 64];
    __shared__ float red[4];
    const int c = blockIdx.x >> 3;
    const int g = blockIdx.x & 7;
    const int tok = c + 1;
    const int t = threadIdx.x;
    const int ybase = 8 * g - 1;

    for (int idx = t; idx < 640; idx += 256) {
        int rr = idx >> 6, x = idx & 63;
        int y = min(max(ybase + rr, 0), 63);
        tile[idx] = attn[(y * 64 + x) * SEQ + tok];
    }
    __syncthreads();

    int x0, x1; float wx;
    coord(t, x0, x1, wx);
    float m = -1e30f;
    int cy0 = -99, cy1 = -99;
    float r0 = 0.f, r1 = 0.f;
    for (int i = 32 * g; i < 32 * g + 32; ++i) {
        int y0, y1; float wy;
        coord(i, y0, y1, wy);
        if (y0 != cy0 || y1 != cy1) {
            int l0 = y0 - ybase, l1 = y1 - ybase;
            if (y0 == cy1) r0 = r1;
            else r0 = tile[l0 * 64 + x0] * (1.f - wx) + tile[l0 * 64 + x1] * wx;
            if (y1 == y0) r1 = r0;
            else r1 = tile[l1 * 64 + x0] * (1.f - wx) + tile[l1 * 64 + x1] * wx;
            cy0 = y0; cy1 = y1;
        }
        m = fmaxf(m, r0 * (1.f - wy) + r1 * wy);
    }
    #pragma unroll
    for (int off = 1; off < 64; off <<= 1)
        m = fmaxf(m, __shfl_xor(m, off, 64));
    if ((t & 63) == 0) red[t >> 6] = m;
    __syncthreads();
    if (t == 0)
        ws_maxpart[blockIdx.x] = fmaxf(fmaxf(red[0], red[1]), fmaxf(red[2], red[3]));
}

// Kernel 2: blocks 0..15 write wj[j] = sum_c (+/-1)*gate[c,j] (FULL overwrite,
// no memset, no atomics; channel maxima reduced in-register from the 64
// partials — fmax is exact so gates are bit-identical to the atomic version).
// Blocks 16..23: cross-attn MSE partial per token, plain store.
__global__ __launch_bounds__(256) void kgates(const float* __restrict__ attn,
                                              const float* __restrict__ attn_e,
                                              const float* __restrict__ ws_maxpart,
                                              float* __restrict__ wj,
                                              float* __restrict__ ws_crosspart) {
    const int bid = blockIdx.x;
    const int t = threadIdx.x;
    if (bid < 16) {
        const int j = bid * 256 + t;
        const int y = j >> 6, x = j & 63;
        float acc = 0.f;
        #pragma unroll
        for (int c = 0; c < 8; ++c) {
            const int tok = c + 1;
            const bool is_tok = (tok == 2) || (tok == 5);
            float mx = ws_maxpart[c * 8];
            #pragma unroll
            for (int g = 1; g < 8; ++g) mx = fmaxf(mx, ws_maxpart[c * 8 + g]);
            const float lim = mx * (is_tok ? 0.85f : 0.95f);
            bool gate = false;
            #pragma unroll
            for (int di = 1; di <= 2; ++di) {
                int y0, y1; float wy;
                coord(4 * y + di, y0, y1, wy);
                #pragma unroll
                for (int dj = 1; dj <= 2; ++dj) {
                    int xa, xb; float wxv;
                    coord(4 * x + dj, xa, xb, wxv);
                    float v00 = attn[(y0 * 64 + xa) * SEQ + tok];
                    float v01 = attn[(y0 * 64 + xb) * SEQ + tok];
                    float v10 = attn[(y1 * 64 + xa) * SEQ + tok];
                    float v11 = attn[(y1 * 64 + xb) * SEQ + tok];
                    float top = v00 * (1.f - wxv) + v01 * wxv;
                    float bot = v10 * (1.f - wxv) + v11 * wxv;
                    float u = top * (1.f - wy) + bot * wy;
                    gate = gate || (u >= lim);
                }
            }
            if (gate) acc += is_tok ? -1.f : 1.f;
        }
        wj[j] = acc;
    } else {
        __shared__ float red[4];
        const int tok = bid - 16 + 1;
        const bool is_tok = (tok == 2) || (tok == 5);
        float sum = 0.f;
        #pragma unroll
        for (int kk = 0; kk < 16; ++kk) {
            int p = t + kk * 256;
            float d = attn[p * SEQ + tok] - attn_e[p * SEQ + tok];
            sum += d * d;
        }
        #pragma unroll
        for (int off = 1; off < 64; off <<= 1) sum += __shfl_xor(sum, off, 64);
        if ((t & 63) == 0) red[t >> 6] = sum;
        __syncthreads();
        if (t == 0)
            ws_crosspart[bid - 16] =
                (is_tok ? -1.f : 1.f) * (red[0] + red[1] + red[2] + red[3]);
    }
}

// Kernel 3: streaming pass. Inline-asm clause: 8 nt global_load_dwordx4
// (saddr form: SGPR base per array + 4 shared byte-offset VGPRs) + ONE
// s_waitcnt vmcnt(0) — forces 8x16B outstanding per thread, no compiler
// partial-wait bubbles. Block b reads one 16KB row per array; the column
// quad of load k is k*256+t -> vw[k] direct.
__global__ __launch_bounds__(256) void kself(const float* __restrict__ a,
                                             const float* __restrict__ b,
                                             const float* __restrict__ wj,
                                             float* __restrict__ ws_partial) {
    __shared__ float red[4];
    const int t = threadIdx.x;
    const unsigned off0 = (unsigned)(blockIdx.x * 1024 + t) * 16u;  // bytes
    const unsigned vo0 = off0;
    const unsigned vo1 = off0 + 4096u;
    const unsigned vo2 = off0 + 8192u;
    const unsigned vo3 = off0 + 12288u;
    f32x4 va0, va1, va2, va3, vb0, vb1, vb2, vb3;
    asm volatile(
        "global_load_dwordx4 %0, %8, %12 nt\n\t"
        "global_load_dwordx4 %1, %9, %12 nt\n\t"
        "global_load_dwordx4 %2, %10, %12 nt\n\t"
        "global_load_dwordx4 %3, %11, %12 nt\n\t"
        "global_load_dwordx4 %4, %8, %13 nt\n\t"
        "global_load_dwordx4 %5, %9, %13 nt\n\t"
        "global_load_dwordx4 %6, %10, %13 nt\n\t"
        "global_load_dwordx4 %7, %11, %13 nt\n\t"
        "s_waitcnt vmcnt(0)"
        : "=&v"(va0), "=&v"(va1), "=&v"(va2), "=&v"(va3),
          "=&v"(vb0), "=&v"(vb1), "=&v"(vb2), "=&v"(vb3)
        : "v"(vo0), "v"(vo1), "v"(vo2), "v"(vo3),
          "s"(a), "s"(b));
    const float4* wj4 = (const float4*)wj;
    float4 vw0 = wj4[t];
    float4 vw1 = wj4[256 + t];
    float4 vw2 = wj4[512 + t];
    float4 vw3 = wj4[768 + t];
    float sum = 0.f;
    {
        float d0 = va0.x - vb0.x, d1 = va0.y - vb0.y;
        float d2 = va0.z - vb0.z, d3 = va0.w - vb0.w;
        sum += vw0.x * d0 * d0 + vw0.y * d1 * d1 + vw0.z * d2 * d2 + vw0.w * d3 * d3;
        d0 = va1.x - vb1.x; d1 = va1.y - vb1.y;
        d2 = va1.z - vb1.z; d3 = va1.w - vb1.w;
        sum += vw1.x * d0 * d0 + vw1.y * d1 * d1 + vw1.z * d2 * d2 + vw1.w * d3 * d3;
        d0 = va2.x - vb2.x; d1 = va2.y - vb2.y;
        d2 = va2.z - vb2.z; d3 = va2.w - vb2.w;
        sum += vw2.x * d0 * d0 + vw2.y * d1 * d1 + vw2.z * d2 * d2 + vw2.w * d3 * d3;
        d0 = va3.x - vb3.x; d1 = va3.y - vb3.y;
        d2 = va3.z - vb3.z; d3 = va3.w - vb3.w;
        sum += vw3.x * d0 * d0 + vw3.y * d1 * d1 + vw3.z * d2 * d2 + vw3.w * d3 * d3;
    }
    #pragma unroll
    for (int off = 1; off < 64; off <<= 1) sum += __shfl_xor(sum, off, 64);
    if ((t & 63) == 0) red[t >> 6] = sum;
    __syncthreads();
    if (t == 0)
        ws_partial[blockIdx.x] = red[0] + red[1] + red[2] + red[3];
}

// Kernel 4: finalize — 1 block sums 4096 partials + 8 cross partials.
__global__ __launch_bounds__(256) void kfin(const float* __restrict__ ws_partial,
                                            const float* __restrict__ ws_crosspart,
                                            float* __restrict__ out) {
    __shared__ float red[4];
    const int t = threadIdx.x;
    float sum = 0.f;
    #pragma unroll
    for (int k = 0; k < 16; ++k) sum += ws_partial[t + k * 256];
    #pragma unroll
    for (int off = 1; off < 64; off <<= 1) sum += __shfl_xor(sum, off, 64);
    if ((t & 63) == 0) red[t >> 6] = sum;
    __syncthreads();
    if (t == 0) {
        float tot = red[0] + red[1] + red[2] + red[3];
        #pragma unroll
        for (int k = 0; k < 8; ++k) tot += ws_crosspart[k];
        out[0] = tot * (1.0f / HWPIX);
    }
}

extern "C" void kernel_launch(void* const* d_in, const int* in_sizes, int n_in,
                              void* d_out, int out_size, void* d_ws, size_t ws_size,
                              hipStream_t stream) {
    const float* attn   = (const float*)d_in[0];
    const float* attn_e = (const float*)d_in[1];
    const float* sa     = (const float*)d_in[2];
    const float* sae    = (const float*)d_in[3];
    float* out = (float*)d_out;
    float* wj      = (float*)d_ws;          // [0,    4096) gate weights (overwritten)
    float* ws_maxp = wj + HWPIX;            // [4096, 4160) 64 max partials
    float* ws_crop = wj + HWPIX + 64;       // [4160, 4168) 8 cross partials
    float* ws_part = wj + 4352;             // [4352, 8448) kself partials

    // no memsets, no atomics: every ws location read is written earlier
    // in the same replay by a plain store.
    kmax  <<<64,        256, 0, stream>>>(attn, ws_maxp);
    kgates<<<24,        256, 0, stream>>>(attn, attn_e, ws_maxp, wj, ws_crop);
    kself <<<NBLK_SELF, 256, 0, stream>>>(sa, sae, wj, ws_part);
    kfin  <<<1,         256, 0, stream>>>(ws_part, ws_crop, out);
}